// Round 11
// baseline (453.879 us; speedup 1.0000x reference)
//
#include <hip/hip_runtime.h>
#include <cstdint>

constexpr int BG = 256;        // graphs
constexpr int MAXN = 2000;
constexpr int NPARTS = 10;

// ---------------- batch boundaries (no atomics; batch is sorted) ----------------

__global__ void k_bounds(const int* __restrict__ batch, int* __restrict__ cum, int N) {
  int i = blockIdx.x * blockDim.x + threadIdx.x;
  if (i >= N) return;
  int b = batch[i];
  if (i == 0) cum[b] = 0;
  else if (batch[i - 1] != b) cum[b] = i;
  if (i == N - 1) cum[BG] = N;
}

// ---------------- CSR build ----------------

__global__ void k_deg_int(const int* __restrict__ dst, int* __restrict__ deg, int E) {
  int e = blockIdx.x * blockDim.x + threadIdx.x;
  if (e < E) atomicAdd(&deg[dst[e]], 1);
}

__global__ void k_blocksum(const int* __restrict__ deg, int* __restrict__ bsum, int N) {
  __shared__ int sd[256];
  int i = blockIdx.x * 256 + threadIdx.x;
  sd[threadIdx.x] = (i < N) ? deg[i] : 0;
  __syncthreads();
  for (int s = 128; s > 0; s >>= 1) {
    if (threadIdx.x < s) sd[threadIdx.x] += sd[threadIdx.x + s];
    __syncthreads();
  }
  if (threadIdx.x == 0) bsum[blockIdx.x] = sd[0];
}

// parallel exclusive scan of bsum[0..nb) with one 256-thread block
__global__ __launch_bounds__(256)
void k_scanb(int* __restrict__ bsum, int nb) {
  __shared__ int part[256];
  int tid = threadIdx.x;
  int per = (nb + 255) / 256;
  int beg = tid * per;
  int end = beg + per; if (end > nb) end = nb;
  int s = 0;
  for (int i = beg; i < end; i++) s += bsum[i];
  part[tid] = s;
  __syncthreads();
  for (int off = 1; off < 256; off <<= 1) {
    int t = (tid >= off) ? part[tid - off] : 0;
    __syncthreads();
    part[tid] += t;
    __syncthreads();
  }
  int run = part[tid] - s;   // exclusive prefix of this chunk
  for (int i = beg; i < end; i++) { int v = bsum[i]; bsum[i] = run; run += v; }
}

// rowptr + dinv fused (deg already loaded here)
__global__ void k_rowptr(const int* __restrict__ deg, const int* __restrict__ bsum,
                         int* __restrict__ rowptr, float* __restrict__ dinvf, int N) {
  __shared__ int sc[256];
  int tid = threadIdx.x;
  int i = blockIdx.x * 256 + tid;
  int v = (i < N) ? deg[i] : 0;
  sc[tid] = v;
  __syncthreads();
  for (int off = 1; off < 256; off <<= 1) {
    int t = (tid >= off) ? sc[tid - off] : 0;
    __syncthreads();
    sc[tid] += t;
    __syncthreads();
  }
  if (i < N) {
    rowptr[i] = bsum[blockIdx.x] + sc[tid] - v;   // exclusive
    dinvf[i] = rsqrtf((float)v + 1.0f);           // +1 self-loop
  }
  if (i == N - 1) rowptr[N] = bsum[blockIdx.x] + sc[tid];  // total = E
}

__global__ void k_fill(const int* __restrict__ src, const int* __restrict__ dst,
                       const int* __restrict__ rowptr, int* __restrict__ cursor,
                       int* __restrict__ adj, int E) {
  int e = blockIdx.x * blockDim.x + threadIdx.x;
  if (e >= E) return;
  int d = dst[e];
  int p = atomicAdd(&cursor[d], 1);
  adj[rowptr[d] + p] = src[e];
}

// ---------------- GCN dense parts ----------------

__global__ void k_xw1(const float* __restrict__ x, const float* __restrict__ W1,
                      const float* __restrict__ dinv, float* __restrict__ A, int N) {
  int i = blockIdx.x * blockDim.x + threadIdx.x;
  if (i >= N) return;
  float4 xi = ((const float4*)x)[i];
  float di = dinv[i];
  #pragma unroll
  for (int c = 0; c < 8; c++) {
    float s = xi.x * W1[c] + xi.y * W1[8 + c] + xi.z * W1[16 + c] + xi.w * W1[24 + c];
    A[(size_t)i * 8 + c] = s * di;
  }
}

__global__ void k_gather_l1(const float* __restrict__ A, const int* __restrict__ rowptr,
                            const int* __restrict__ adj, const float* __restrict__ dinv,
                            const float* __restrict__ b1, const float* __restrict__ W2,
                            float* __restrict__ A2, int N) {
  int i = blockIdx.x * blockDim.x + threadIdx.x;
  if (i >= N) return;
  const float4* Ai = (const float4*)(A + (size_t)i * 8);
  float4 s0 = Ai[0], s1 = Ai[1];
  int beg = rowptr[i], end = rowptr[i + 1];
  for (int j = beg; j < end; j++) {
    const float4* As = (const float4*)(A + (size_t)adj[j] * 8);
    float4 a0 = As[0], a1 = As[1];
    s0.x += a0.x; s0.y += a0.y; s0.z += a0.z; s0.w += a0.w;
    s1.x += a1.x; s1.y += a1.y; s1.z += a1.z; s1.w += a1.w;
  }
  float di = dinv[i];
  float h[8];
  h[0] = fmaxf(s0.x * di + b1[0], 0.f); h[1] = fmaxf(s0.y * di + b1[1], 0.f);
  h[2] = fmaxf(s0.z * di + b1[2], 0.f); h[3] = fmaxf(s0.w * di + b1[3], 0.f);
  h[4] = fmaxf(s1.x * di + b1[4], 0.f); h[5] = fmaxf(s1.y * di + b1[5], 0.f);
  h[6] = fmaxf(s1.z * di + b1[6], 0.f); h[7] = fmaxf(s1.w * di + b1[7], 0.f);
  #pragma unroll
  for (int c = 0; c < 8; c++) {
    float a = 0.f;
    #pragma unroll
    for (int k = 0; k < 8; k++) a += h[k] * W2[k * 8 + c];
    A2[(size_t)i * 8 + c] = a * di;
  }
}

__global__ void k_gather_l2(const float* __restrict__ A2, const int* __restrict__ rowptr,
                            const int* __restrict__ adj, const float* __restrict__ dinv,
                            const float* __restrict__ b2, const int* __restrict__ batch,
                            const int* __restrict__ cum, float* __restrict__ dense, int N) {
  int i = blockIdx.x * blockDim.x + threadIdx.x;
  if (i >= N) return;
  const float4* Ai = (const float4*)(A2 + (size_t)i * 8);
  float4 s0 = Ai[0], s1 = Ai[1];
  int beg = rowptr[i], end = rowptr[i + 1];
  for (int j = beg; j < end; j++) {
    const float4* As = (const float4*)(A2 + (size_t)adj[j] * 8);
    float4 a0 = As[0], a1 = As[1];
    s0.x += a0.x; s0.y += a0.y; s0.z += a0.z; s0.w += a0.w;
    s1.x += a1.x; s1.y += a1.y; s1.z += a1.z; s1.w += a1.w;
  }
  float di = dinv[i];
  float h[8];
  h[0] = fmaxf(s0.x * di + b2[0], 0.f); h[1] = fmaxf(s0.y * di + b2[1], 0.f);
  h[2] = fmaxf(s0.z * di + b2[2], 0.f); h[3] = fmaxf(s0.w * di + b2[3], 0.f);
  h[4] = fmaxf(s1.x * di + b2[4], 0.f); h[5] = fmaxf(s1.y * di + b2[5], 0.f);
  h[6] = fmaxf(s1.z * di + b2[6], 0.f); h[7] = fmaxf(s1.w * di + b2[7], 0.f);
  int b = batch[i];
  int pos = i - cum[b];
  #pragma unroll
  for (int c = 0; c < 8; c++)
    dense[((size_t)(b * 8 + c)) * MAXN + pos] = h[c];
}

// ---------------- conv1d(k=5,'same') + relu + mean-pool2 — NP=4, true prefetch ----------------
// grid (BG, COG, LT) = 1024 blocks (4/CU). __launch_bounds__(256,4) -> VGPR cap 128 so
// the ci+1 prefetch registers actually live alongside acc[4][8].
// Lane -> 4 pooled positions (8 conv cols). Inputs: 4 aligned float4 per ci; bases clamped
// to [0,L-4] (right-overrun feeds only unstored/unread outputs); left edge zeroes cols.
template<int CIN, int COUT, int L, int COG>
__global__ __launch_bounds__(256, 4)
void k_conv(const float* __restrict__ in, const float* __restrict__ w,
            const float* __restrict__ bias, float* __restrict__ out) {
  constexpr int LOUT = L / 2;
  constexpr int COPB = COUT / COG;      // out-channels per block (16)
  constexpr int NCO = COPB / 4;         // out-channels per wave (4)
  constexpr int TP = 256;               // pooled positions per tile
  constexpr int WS = COPB + 4;          // padded co-stride
  __shared__ float wT[CIN * 5 * WS];

  const int co0b = blockIdx.y * COPB;
  for (int t = threadIdx.x; t < COPB * CIN * 5; t += 256) {
    int col = t / (CIN * 5), r = t % (CIN * 5);
    wT[r * WS + col] = w[(size_t)(co0b + col) * CIN * 5 + r];
  }
  __syncthreads();

  const int lane = threadIdx.x & 63;
  const int wv = threadIdx.x >> 6;
  const int co0 = wv * NCO;
  const int p0 = blockIdx.z * TP + lane * 4;   // first pooled pos (mult of 4)
  const int a0 = 2 * p0 - 4;                   // aligned load base
  const bool lz = (p0 == 0);
  const float* __restrict__ inb = in + (size_t)blockIdx.x * CIN * L;

  int bas[4];
  #pragma unroll
  for (int m = 0; m < 4; m++) {
    int rb = a0 + 4 * m;
    rb = rb < 0 ? 0 : rb;
    bas[m] = rb > (L - 4) ? (L - 4) : rb;
  }

  float acc[NCO][8];
  #pragma unroll
  for (int g = 0; g < NCO; g++)
    #pragma unroll
    for (int p = 0; p < 8; p++) acc[g][p] = 0.f;

  // prefetch ci = 0
  float4 nxt0 = *(const float4*)(inb + bas[0]);
  float4 nxt1 = *(const float4*)(inb + bas[1]);
  float4 nxt2 = *(const float4*)(inb + bas[2]);
  float4 nxt3 = *(const float4*)(inb + bas[3]);

  const float* src = inb;
  for (int ci = 0; ci < CIN; ci++) {
    // r[0..15] = cols a0 .. a0+15 ; col (i0+j) = r[j+2]
    float r[16];
    r[0] = nxt0.x; r[1] = nxt0.y; r[2] = nxt0.z; r[3] = nxt0.w;
    r[4] = nxt1.x; r[5] = nxt1.y; r[6] = nxt1.z; r[7] = nxt1.w;
    r[8] = nxt2.x; r[9] = nxt2.y; r[10] = nxt2.z; r[11] = nxt2.w;
    r[12] = nxt3.x; r[13] = nxt3.y; r[14] = nxt3.z; r[15] = nxt3.w;
    if (lz) { r[2] = 0.f; r[3] = 0.f; }   // zero cols -2,-1 (left pad)

    if (ci + 1 < CIN) {   // issue next-ci loads; latency hides under the FMA block
      src += L;
      nxt0 = *(const float4*)(src + bas[0]);
      nxt1 = *(const float4*)(src + bas[1]);
      nxt2 = *(const float4*)(src + bas[2]);
      nxt3 = *(const float4*)(src + bas[3]);
    }

    const float* wb = &wT[(ci * 5) * WS + co0];
    float4 w0 = *(const float4*)(wb);
    float4 w1 = *(const float4*)(wb + WS);
    float4 w2 = *(const float4*)(wb + 2 * WS);
    float4 w3 = *(const float4*)(wb + 3 * WS);
    float4 w4 = *(const float4*)(wb + 4 * WS);
    #pragma unroll
    for (int cc = 0; cc < 4; cc++) {
      float v0 = cc == 0 ? w0.x : cc == 1 ? w0.y : cc == 2 ? w0.z : w0.w;
      float v1 = cc == 0 ? w1.x : cc == 1 ? w1.y : cc == 2 ? w1.z : w1.w;
      float v2 = cc == 0 ? w2.x : cc == 1 ? w2.y : cc == 2 ? w2.z : w2.w;
      float v3 = cc == 0 ? w3.x : cc == 1 ? w3.y : cc == 2 ? w3.z : w3.w;
      float v4 = cc == 0 ? w4.x : cc == 1 ? w4.y : cc == 2 ? w4.z : w4.w;
      #pragma unroll
      for (int p = 0; p < 8; p++)
        acc[cc][p] += v0 * r[p + 2] + v1 * r[p + 3] + v2 * r[p + 4]
                    + v3 * r[p + 5] + v4 * r[p + 6];
    }
  }

  #pragma unroll
  for (int g = 0; g < NCO; g++) {
    int co = co0b + co0 + g;
    float bv = bias[co];
    float tmp[4];
    #pragma unroll
    for (int m = 0; m < 4; m++) {
      float y0 = fmaxf(acc[g][2 * m] + bv, 0.f);
      float y1 = fmaxf(acc[g][2 * m + 1] + bv, 0.f);
      tmp[m] = 0.5f * (y0 + y1);
    }
    float* op = out + (size_t)(blockIdx.x * COUT + co) * LOUT + p0;
    if constexpr (LOUT % 4 == 0) {
      if (p0 + 4 <= LOUT) {
        *(float4*)op = make_float4(tmp[0], tmp[1], tmp[2], tmp[3]);
      } else {
        #pragma unroll
        for (int m = 0; m < 4; m++) if (p0 + m < LOUT) op[m] = tmp[m];
      }
    } else {  // LOUT % 2 == 0 (conv3: 250)
      #pragma unroll
      for (int m2 = 0; m2 < 2; m2++) {
        int p = p0 + 2 * m2;
        if (p + 1 < LOUT) {
          *(float2*)(op + 2 * m2) = make_float2(tmp[2 * m2], tmp[2 * m2 + 1]);
        } else if (p < LOUT) {
          op[2 * m2] = tmp[2 * m2];
        }
      }
    }
  }
}

// ---------------- fused head: segment means + MLP (one block per graph) ----------------
__global__ __launch_bounds__(256)
void k_head(const float* __restrict__ xp, const int* __restrict__ cum,
            const float* __restrict__ fw1, const float* __restrict__ fb1,
            const float* __restrict__ fw2, const float* __restrict__ fb2,
            float* __restrict__ out) {
  constexpr int LC = MAXN / 8;   // 250
  __shared__ float seg[640];
  __shared__ float hid[100];
  int b = blockIdx.x;
  int valid = (cum[b + 1] - cum[b]) >> 3;
  int base = valid / NPARTS, rem = valid % NPARTS;
  for (int idx = threadIdx.x; idx < 64 * NPARTS; idx += 256) {
    int c = idx / NPARTS, j = idx % NPARTS;
    int size = base + (j < rem ? 1 : 0);
    int start = j * base + (j < rem ? j : rem);
    const float* p = xp + ((size_t)b * 64 + c) * LC + start;
    float s = 0.f;
    for (int t = 0; t < size; t++) s += p[t];
    seg[idx] = s / (float)size;   // seg[c*10+j]
  }
  __syncthreads();
  int t = threadIdx.x;
  if (t < 100) {
    float acc = fb1[t];
    for (int k = 0; k < 640; k++) acc += seg[k] * fw1[(size_t)k * 100 + t];
    hid[t] = fmaxf(acc, 0.f);
  }
  __syncthreads();
  if (t < 2) {
    float acc = fb2[t];
    for (int k = 0; k < 100; k++) acc += hid[k] * fw2[k * 2 + t];
    out[b * 2 + t] = acc;
  }
}

extern "C" void kernel_launch(void* const* d_in, const int* in_sizes, int n_in,
                              void* d_out, int out_size, void* d_ws, size_t ws_size,
                              hipStream_t stream) {
  const float* x   = (const float*)d_in[0];
  const int*   ei  = (const int*)d_in[1];
  const int* batch = (const int*)d_in[2];
  const float* W1  = (const float*)d_in[3];
  const float* b1  = (const float*)d_in[4];
  const float* W2  = (const float*)d_in[5];
  const float* b2  = (const float*)d_in[6];
  const float* cw1 = (const float*)d_in[7];
  const float* cb1 = (const float*)d_in[8];
  const float* cw2 = (const float*)d_in[9];
  const float* cb2 = (const float*)d_in[10];
  const float* cw3 = (const float*)d_in[11];
  const float* cb3 = (const float*)d_in[12];
  const float* fw1 = (const float*)d_in[13];
  const float* fb1 = (const float*)d_in[14];
  const float* fw2 = (const float*)d_in[15];
  const float* fb2 = (const float*)d_in[16];
  float* outp = (float*)d_out;

  int N = in_sizes[0] / 4;
  int E = in_sizes[1] / 2;
  size_t N8 = (size_t)N * 8;
  int nbN = (N + 255) / 256, nbE = (E + 255) / 256;

  float* wsf  = (float*)d_ws;
  float* A    = wsf;
  float* Bb   = A + N8;              // A2 for layer 2
  int* degI   = (int*)(Bb + N8);     // N ints
  int* cursor = degI + N;            // N ints (adjacent -> one memset)
  float* dinv = (float*)(cursor + N);// N floats
  int* cum    = (int*)(dinv + N);    // BG+1 ints
  float* D0   = (float*)(((uintptr_t)(cum + BG + 1) + 255) & ~(uintptr_t)255);
  float* D1   = D0 + (size_t)BG * 8 * MAXN;

  // CSR temporaries aliased into D1 (D1 first written by conv1, after fill/gathers)
  int* rowptr = (int*)D1;            // N+1
  int* adj    = rowptr + (N + 1);    // E
  int* bsum   = adj + E;             // nbN

  // --- boundaries (no atomics) ---
  k_bounds<<<nbN, 256, 0, stream>>>(batch, cum, N);

  // --- CSR build ---
  hipMemsetAsync(degI, 0, 2 * (size_t)N * sizeof(int), stream);   // degI + cursor
  k_deg_int<<<nbE, 256, 0, stream>>>(ei + E, degI, E);
  k_blocksum<<<nbN, 256, 0, stream>>>(degI, bsum, N);
  k_scanb<<<1, 256, 0, stream>>>(bsum, nbN);
  k_rowptr<<<nbN, 256, 0, stream>>>(degI, bsum, rowptr, dinv, N);
  k_fill<<<nbE, 256, 0, stream>>>(ei, ei + E, rowptr, cursor, adj, E);

  // --- GCN (gather, no atomics) ---
  k_xw1<<<nbN, 256, 0, stream>>>(x, W1, dinv, A, N);
  k_gather_l1<<<nbN, 256, 0, stream>>>(A, rowptr, adj, dinv, b1, W2, Bb, N);
  hipMemsetAsync(D0, 0, (size_t)BG * 8 * MAXN * sizeof(float), stream);
  k_gather_l2<<<nbN, 256, 0, stream>>>(Bb, rowptr, adj, dinv, b2, batch, cum, D0, N);

  // --- convs: NP=4, COPB=16, 1024 blocks (4/CU), real prefetch via launch_bounds(256,4) ---
  k_conv<8, 16, 2000, 1><<<dim3(BG, 1, 4), 256, 0, stream>>>(D0, cw1, cb1, D1);
  k_conv<16, 32, 1000, 2><<<dim3(BG, 2, 2), 256, 0, stream>>>(D1, cw2, cb2, D0);
  k_conv<32, 64, 500, 4><<<dim3(BG, 4, 1), 256, 0, stream>>>(D0, cw3, cb3, D1);

  // --- fused segment means + MLP ---
  k_head<<<BG, 256, 0, stream>>>(D1, cum, fw1, fb1, fw2, fb2, outp);
}

// Round 12
// 175.785 us; speedup vs baseline: 2.5820x; 2.5820x over previous
//
#include <hip/hip_runtime.h>
#include <cstdint>

constexpr int BG = 256;        // graphs
constexpr int MAXN = 2000;
constexpr int NPARTS = 10;

// ---------------- batch boundaries (no atomics; batch is sorted) ----------------

__global__ void k_bounds(const int* __restrict__ batch, int* __restrict__ cum, int N) {
  int i = blockIdx.x * blockDim.x + threadIdx.x;
  if (i >= N) return;
  int b = batch[i];
  if (i == 0) cum[b] = 0;
  else if (batch[i - 1] != b) cum[b] = i;
  if (i == N - 1) cum[BG] = N;
}

// ---------------- CSR build ----------------

__global__ void k_deg_int(const int* __restrict__ dst, int* __restrict__ deg, int E) {
  int e = blockIdx.x * blockDim.x + threadIdx.x;
  if (e < E) atomicAdd(&deg[dst[e]], 1);
}

__global__ void k_blocksum(const int* __restrict__ deg, int* __restrict__ bsum, int N) {
  __shared__ int sd[256];
  int i = blockIdx.x * 256 + threadIdx.x;
  sd[threadIdx.x] = (i < N) ? deg[i] : 0;
  __syncthreads();
  for (int s = 128; s > 0; s >>= 1) {
    if (threadIdx.x < s) sd[threadIdx.x] += sd[threadIdx.x + s];
    __syncthreads();
  }
  if (threadIdx.x == 0) bsum[blockIdx.x] = sd[0];
}

// parallel exclusive scan of bsum[0..nb) with one 256-thread block
__global__ __launch_bounds__(256)
void k_scanb(int* __restrict__ bsum, int nb) {
  __shared__ int part[256];
  int tid = threadIdx.x;
  int per = (nb + 255) / 256;
  int beg = tid * per;
  int end = beg + per; if (end > nb) end = nb;
  int s = 0;
  for (int i = beg; i < end; i++) s += bsum[i];
  part[tid] = s;
  __syncthreads();
  for (int off = 1; off < 256; off <<= 1) {
    int t = (tid >= off) ? part[tid - off] : 0;
    __syncthreads();
    part[tid] += t;
    __syncthreads();
  }
  int run = part[tid] - s;   // exclusive prefix of this chunk
  for (int i = beg; i < end; i++) { int v = bsum[i]; bsum[i] = run; run += v; }
}

// rowptr + dinv fused (deg already loaded here)
__global__ void k_rowptr(const int* __restrict__ deg, const int* __restrict__ bsum,
                         int* __restrict__ rowptr, float* __restrict__ dinvf, int N) {
  __shared__ int sc[256];
  int tid = threadIdx.x;
  int i = blockIdx.x * 256 + tid;
  int v = (i < N) ? deg[i] : 0;
  sc[tid] = v;
  __syncthreads();
  for (int off = 1; off < 256; off <<= 1) {
    int t = (tid >= off) ? sc[tid - off] : 0;
    __syncthreads();
    sc[tid] += t;
    __syncthreads();
  }
  if (i < N) {
    rowptr[i] = bsum[blockIdx.x] + sc[tid] - v;   // exclusive
    dinvf[i] = rsqrtf((float)v + 1.0f);           // +1 self-loop
  }
  if (i == N - 1) rowptr[N] = bsum[blockIdx.x] + sc[tid];  // total = E
}

__global__ void k_fill(const int* __restrict__ src, const int* __restrict__ dst,
                       const int* __restrict__ rowptr, int* __restrict__ cursor,
                       int* __restrict__ adj, int E) {
  int e = blockIdx.x * blockDim.x + threadIdx.x;
  if (e >= E) return;
  int d = dst[e];
  int p = atomicAdd(&cursor[d], 1);
  adj[rowptr[d] + p] = src[e];
}

// ---------------- GCN dense parts ----------------

__global__ void k_xw1(const float* __restrict__ x, const float* __restrict__ W1,
                      const float* __restrict__ dinv, float* __restrict__ A, int N) {
  int i = blockIdx.x * blockDim.x + threadIdx.x;
  if (i >= N) return;
  float4 xi = ((const float4*)x)[i];
  float di = dinv[i];
  #pragma unroll
  for (int c = 0; c < 8; c++) {
    float s = xi.x * W1[c] + xi.y * W1[8 + c] + xi.z * W1[16 + c] + xi.w * W1[24 + c];
    A[(size_t)i * 8 + c] = s * di;
  }
}

__global__ void k_gather_l1(const float* __restrict__ A, const int* __restrict__ rowptr,
                            const int* __restrict__ adj, const float* __restrict__ dinv,
                            const float* __restrict__ b1, const float* __restrict__ W2,
                            float* __restrict__ A2, int N) {
  int i = blockIdx.x * blockDim.x + threadIdx.x;
  if (i >= N) return;
  const float4* Ai = (const float4*)(A + (size_t)i * 8);
  float4 s0 = Ai[0], s1 = Ai[1];
  int beg = rowptr[i], end = rowptr[i + 1];
  for (int j = beg; j < end; j++) {
    const float4* As = (const float4*)(A + (size_t)adj[j] * 8);
    float4 a0 = As[0], a1 = As[1];
    s0.x += a0.x; s0.y += a0.y; s0.z += a0.z; s0.w += a0.w;
    s1.x += a1.x; s1.y += a1.y; s1.z += a1.z; s1.w += a1.w;
  }
  float di = dinv[i];
  float h[8];
  h[0] = fmaxf(s0.x * di + b1[0], 0.f); h[1] = fmaxf(s0.y * di + b1[1], 0.f);
  h[2] = fmaxf(s0.z * di + b1[2], 0.f); h[3] = fmaxf(s0.w * di + b1[3], 0.f);
  h[4] = fmaxf(s1.x * di + b1[4], 0.f); h[5] = fmaxf(s1.y * di + b1[5], 0.f);
  h[6] = fmaxf(s1.z * di + b1[6], 0.f); h[7] = fmaxf(s1.w * di + b1[7], 0.f);
  #pragma unroll
  for (int c = 0; c < 8; c++) {
    float a = 0.f;
    #pragma unroll
    for (int k = 0; k < 8; k++) a += h[k] * W2[k * 8 + c];
    A2[(size_t)i * 8 + c] = a * di;
  }
}

__global__ void k_gather_l2(const float* __restrict__ A2, const int* __restrict__ rowptr,
                            const int* __restrict__ adj, const float* __restrict__ dinv,
                            const float* __restrict__ b2, const int* __restrict__ batch,
                            const int* __restrict__ cum, float* __restrict__ dense, int N) {
  int i = blockIdx.x * blockDim.x + threadIdx.x;
  if (i >= N) return;
  const float4* Ai = (const float4*)(A2 + (size_t)i * 8);
  float4 s0 = Ai[0], s1 = Ai[1];
  int beg = rowptr[i], end = rowptr[i + 1];
  for (int j = beg; j < end; j++) {
    const float4* As = (const float4*)(A2 + (size_t)adj[j] * 8);
    float4 a0 = As[0], a1 = As[1];
    s0.x += a0.x; s0.y += a0.y; s0.z += a0.z; s0.w += a0.w;
    s1.x += a1.x; s1.y += a1.y; s1.z += a1.z; s1.w += a1.w;
  }
  float di = dinv[i];
  float h[8];
  h[0] = fmaxf(s0.x * di + b2[0], 0.f); h[1] = fmaxf(s0.y * di + b2[1], 0.f);
  h[2] = fmaxf(s0.z * di + b2[2], 0.f); h[3] = fmaxf(s0.w * di + b2[3], 0.f);
  h[4] = fmaxf(s1.x * di + b2[4], 0.f); h[5] = fmaxf(s1.y * di + b2[5], 0.f);
  h[6] = fmaxf(s1.z * di + b2[6], 0.f); h[7] = fmaxf(s1.w * di + b2[7], 0.f);
  int b = batch[i];
  int pos = i - cum[b];
  #pragma unroll
  for (int c = 0; c < 8; c++)
    dense[((size_t)(b * 8 + c)) * MAXN + pos] = h[c];
}

// ---------------- conv1d(k=5,'same') + relu + mean-pool2 — 2 graphs/block, prefetch ----------------
// grid (BG/2, COG, LT). __launch_bounds__(256,2) -> VGPR cap 256: room for
// acc[2][4][8] (64) + prefetch nxt[2][4] (32) + weights (20) without spill/remat.
template<int CIN, int COUT, int L, int COG>
__global__ __launch_bounds__(256, 2)
void k_conv(const float* __restrict__ in, const float* __restrict__ w,
            const float* __restrict__ bias, float* __restrict__ out) {
  constexpr int GP = 2;
  constexpr int GB = BG / GP;           // 128
  constexpr int LOUT = L / 2;
  constexpr int COPB = COUT / COG;      // out-channels per block
  constexpr int NCO = COPB / 4;         // out-channels per wave
  constexpr int TP = 256;               // pooled positions per tile
  constexpr int WS = COPB + 4;          // padded co-stride
  __shared__ float wT[CIN * 5 * WS];

  const int co0b = blockIdx.y * COPB;
  for (int t = threadIdx.x; t < COPB * CIN * 5; t += 256) {
    int col = t / (CIN * 5), r = t % (CIN * 5);
    wT[r * WS + col] = w[(size_t)(co0b + col) * CIN * 5 + r];
  }
  __syncthreads();

  const int lane = threadIdx.x & 63;
  const int wv = threadIdx.x >> 6;
  const int co0 = wv * NCO;
  const int p0 = blockIdx.z * TP + lane * 4;   // first pooled pos (mult of 4)
  const int a0 = 2 * p0 - 4;                   // aligned load base
  const bool lz = (p0 == 0);

  int bas[4];
  #pragma unroll
  for (int m = 0; m < 4; m++) {
    int rb = a0 + 4 * m;
    rb = rb < 0 ? 0 : rb;
    bas[m] = rb > (L - 4) ? (L - 4) : rb;
  }

  const float* src[GP];
  #pragma unroll
  for (int gp = 0; gp < GP; gp++)
    src[gp] = in + (size_t)(blockIdx.x + gp * GB) * CIN * L;

  float acc[GP][NCO][8];
  #pragma unroll
  for (int gp = 0; gp < GP; gp++)
    #pragma unroll
    for (int g = 0; g < NCO; g++)
      #pragma unroll
      for (int p = 0; p < 8; p++) acc[gp][g][p] = 0.f;

  // prefetch ci=0
  float4 nxt[GP][4];
  #pragma unroll
  for (int gp = 0; gp < GP; gp++)
    #pragma unroll
    for (int m = 0; m < 4; m++)
      nxt[gp][m] = *(const float4*)(src[gp] + bas[m]);

  for (int ci = 0; ci < CIN; ci++) {
    float4 cur[GP][4];
    #pragma unroll
    for (int gp = 0; gp < GP; gp++)
      #pragma unroll
      for (int m = 0; m < 4; m++) cur[gp][m] = nxt[gp][m];

    if (ci + 1 < CIN) {   // issue next-ci loads; latency hides under FMAs below
      #pragma unroll
      for (int gp = 0; gp < GP; gp++) {
        src[gp] += L;
        #pragma unroll
        for (int m = 0; m < 4; m++)
          nxt[gp][m] = *(const float4*)(src[gp] + bas[m]);
      }
    }

    float f[GP][12];
    #pragma unroll
    for (int gp = 0; gp < GP; gp++) {
      float r[16];
      #pragma unroll
      for (int m = 0; m < 4; m++) {
        r[4 * m] = cur[gp][m].x; r[4 * m + 1] = cur[gp][m].y;
        r[4 * m + 2] = cur[gp][m].z; r[4 * m + 3] = cur[gp][m].w;
      }
      #pragma unroll
      for (int j = 0; j < 12; j++) f[gp][j] = r[j + 2];
      if (lz) { f[gp][0] = 0.f; f[gp][1] = 0.f; }
    }

    #pragma unroll
    for (int q = 0; q < NCO / 4; q++) {
      const float* wb = &wT[(ci * 5) * WS + co0 + 4 * q];
      float4 w0 = *(const float4*)(wb);
      float4 w1 = *(const float4*)(wb + WS);
      float4 w2 = *(const float4*)(wb + 2 * WS);
      float4 w3 = *(const float4*)(wb + 3 * WS);
      float4 w4 = *(const float4*)(wb + 4 * WS);
      #pragma unroll
      for (int cc = 0; cc < 4; cc++) {
        int g = 4 * q + cc;
        float v0 = cc == 0 ? w0.x : cc == 1 ? w0.y : cc == 2 ? w0.z : w0.w;
        float v1 = cc == 0 ? w1.x : cc == 1 ? w1.y : cc == 2 ? w1.z : w1.w;
        float v2 = cc == 0 ? w2.x : cc == 1 ? w2.y : cc == 2 ? w2.z : w2.w;
        float v3 = cc == 0 ? w3.x : cc == 1 ? w3.y : cc == 2 ? w3.z : w3.w;
        float v4 = cc == 0 ? w4.x : cc == 1 ? w4.y : cc == 2 ? w4.z : w4.w;
        #pragma unroll
        for (int gp = 0; gp < GP; gp++)
          #pragma unroll
          for (int p = 0; p < 8; p++)
            acc[gp][g][p] += v0 * f[gp][p] + v1 * f[gp][p + 1] + v2 * f[gp][p + 2]
                           + v3 * f[gp][p + 3] + v4 * f[gp][p + 4];
      }
    }
  }

  #pragma unroll
  for (int gp = 0; gp < GP; gp++) {
    const int bbg = blockIdx.x + gp * GB;
    #pragma unroll
    for (int g = 0; g < NCO; g++) {
      int co = co0b + co0 + g;
      float bv = bias[co];
      float tmp[4];
      #pragma unroll
      for (int m = 0; m < 4; m++) {
        float y0 = fmaxf(acc[gp][g][2 * m] + bv, 0.f);
        float y1 = fmaxf(acc[gp][g][2 * m + 1] + bv, 0.f);
        tmp[m] = 0.5f * (y0 + y1);
      }
      float* op = out + (size_t)(bbg * COUT + co) * LOUT + p0;
      if constexpr (LOUT % 4 == 0) {
        if (p0 + 4 <= LOUT) {
          *(float4*)op = make_float4(tmp[0], tmp[1], tmp[2], tmp[3]);
        } else {
          #pragma unroll
          for (int m = 0; m < 4; m++) if (p0 + m < LOUT) op[m] = tmp[m];
        }
      } else {  // LOUT % 2 == 0 (conv3: 250)
        #pragma unroll
        for (int m2 = 0; m2 < 2; m2++) {
          int p = p0 + 2 * m2;
          if (p + 1 < LOUT) {
            *(float2*)(op + 2 * m2) = make_float2(tmp[2 * m2], tmp[2 * m2 + 1]);
          } else if (p < LOUT) {
            op[2 * m2] = tmp[2 * m2];
          }
        }
      }
    }
  }
}

// ---------------- fused head: segment means + MLP (one block per graph) ----------------
__global__ __launch_bounds__(256)
void k_head(const float* __restrict__ xp, const int* __restrict__ cum,
            const float* __restrict__ fw1, const float* __restrict__ fb1,
            const float* __restrict__ fw2, const float* __restrict__ fb2,
            float* __restrict__ out) {
  constexpr int LC = MAXN / 8;   // 250
  __shared__ float seg[640];
  __shared__ float hid[100];
  int b = blockIdx.x;
  int valid = (cum[b + 1] - cum[b]) >> 3;
  int base = valid / NPARTS, rem = valid % NPARTS;
  for (int idx = threadIdx.x; idx < 64 * NPARTS; idx += 256) {
    int c = idx / NPARTS, j = idx % NPARTS;
    int size = base + (j < rem ? 1 : 0);
    int start = j * base + (j < rem ? j : rem);
    const float* p = xp + ((size_t)b * 64 + c) * LC + start;
    float s = 0.f;
    for (int t = 0; t < size; t++) s += p[t];
    seg[idx] = s / (float)size;   // seg[c*10+j]
  }
  __syncthreads();
  int t = threadIdx.x;
  if (t < 100) {
    float acc = fb1[t];
    for (int k = 0; k < 640; k++) acc += seg[k] * fw1[(size_t)k * 100 + t];
    hid[t] = fmaxf(acc, 0.f);
  }
  __syncthreads();
  if (t < 2) {
    float acc = fb2[t];
    for (int k = 0; k < 100; k++) acc += hid[k] * fw2[k * 2 + t];
    out[b * 2 + t] = acc;
  }
}

extern "C" void kernel_launch(void* const* d_in, const int* in_sizes, int n_in,
                              void* d_out, int out_size, void* d_ws, size_t ws_size,
                              hipStream_t stream) {
  const float* x   = (const float*)d_in[0];
  const int*   ei  = (const int*)d_in[1];
  const int* batch = (const int*)d_in[2];
  const float* W1  = (const float*)d_in[3];
  const float* b1  = (const float*)d_in[4];
  const float* W2  = (const float*)d_in[5];
  const float* b2  = (const float*)d_in[6];
  const float* cw1 = (const float*)d_in[7];
  const float* cb1 = (const float*)d_in[8];
  const float* cw2 = (const float*)d_in[9];
  const float* cb2 = (const float*)d_in[10];
  const float* cw3 = (const float*)d_in[11];
  const float* cb3 = (const float*)d_in[12];
  const float* fw1 = (const float*)d_in[13];
  const float* fb1 = (const float*)d_in[14];
  const float* fw2 = (const float*)d_in[15];
  const float* fb2 = (const float*)d_in[16];
  float* outp = (float*)d_out;

  int N = in_sizes[0] / 4;
  int E = in_sizes[1] / 2;
  size_t N8 = (size_t)N * 8;
  int nbN = (N + 255) / 256, nbE = (E + 255) / 256;

  float* wsf  = (float*)d_ws;
  float* A    = wsf;
  float* Bb   = A + N8;              // A2 for layer 2
  int* degI   = (int*)(Bb + N8);     // N ints
  int* cursor = degI + N;            // N ints (adjacent -> one memset)
  float* dinv = (float*)(cursor + N);// N floats
  int* cum    = (int*)(dinv + N);    // BG+1 ints
  float* D0   = (float*)(((uintptr_t)(cum + BG + 1) + 255) & ~(uintptr_t)255);
  float* D1   = D0 + (size_t)BG * 8 * MAXN;

  // CSR temporaries aliased into D1 (D1 first written by conv1, after fill/gathers)
  int* rowptr = (int*)D1;            // N+1
  int* adj    = rowptr + (N + 1);    // E
  int* bsum   = adj + E;             // nbN

  // --- boundaries (no atomics) ---
  k_bounds<<<nbN, 256, 0, stream>>>(batch, cum, N);

  // --- CSR build ---
  hipMemsetAsync(degI, 0, 2 * (size_t)N * sizeof(int), stream);   // degI + cursor
  k_deg_int<<<nbE, 256, 0, stream>>>(ei + E, degI, E);
  k_blocksum<<<nbN, 256, 0, stream>>>(degI, bsum, N);
  k_scanb<<<1, 256, 0, stream>>>(bsum, nbN);
  k_rowptr<<<nbN, 256, 0, stream>>>(degI, bsum, rowptr, dinv, N);
  k_fill<<<nbE, 256, 0, stream>>>(ei, ei + E, rowptr, cursor, adj, E);

  // --- GCN (gather, no atomics) ---
  k_xw1<<<nbN, 256, 0, stream>>>(x, W1, dinv, A, N);
  k_gather_l1<<<nbN, 256, 0, stream>>>(A, rowptr, adj, dinv, b1, W2, Bb, N);
  hipMemsetAsync(D0, 0, (size_t)BG * 8 * MAXN * sizeof(float), stream);
  k_gather_l2<<<nbN, 256, 0, stream>>>(Bb, rowptr, adj, dinv, b2, batch, cum, D0, N);

  // --- convs: 2 graphs/block, prefetch pipeline, VGPR cap 256 via (256,2) ---
  k_conv<8, 16, 2000, 1><<<dim3(BG / 2, 1, 4), 256, 0, stream>>>(D0, cw1, cb1, D1);
  k_conv<16, 32, 1000, 2><<<dim3(BG / 2, 2, 2), 256, 0, stream>>>(D1, cw2, cb2, D0);
  k_conv<32, 64, 500, 4><<<dim3(BG / 2, 4, 1), 256, 0, stream>>>(D0, cw3, cb3, D1);

  // --- fused segment means + MLP ---
  k_head<<<BG, 256, 0, stream>>>(D1, cum, fw1, fb1, fw2, fb2, outp);
}

// Round 13
// 162.421 us; speedup vs baseline: 2.7945x; 1.0823x over previous
//
#include <hip/hip_runtime.h>
#include <cstdint>

constexpr int BG = 256;        // graphs
constexpr int MAXN = 2000;
constexpr int NPARTS = 10;

// ---------------- batch boundaries (no atomics; batch is sorted) ----------------

__global__ void k_bounds(const int* __restrict__ batch, int* __restrict__ cum, int N) {
  int i = blockIdx.x * blockDim.x + threadIdx.x;
  if (i >= N) return;
  int b = batch[i];
  if (i == 0) cum[b] = 0;
  else if (batch[i - 1] != b) cum[b] = i;
  if (i == N - 1) cum[BG] = N;
}

// ---------------- CSR build ----------------

__global__ void k_deg_int(const int* __restrict__ dst, int* __restrict__ deg, int E) {
  int e = blockIdx.x * blockDim.x + threadIdx.x;
  if (e < E) atomicAdd(&deg[dst[e]], 1);
}

__global__ void k_blocksum(const int* __restrict__ deg, int* __restrict__ bsum, int N) {
  __shared__ int sd[256];
  int i = blockIdx.x * 256 + threadIdx.x;
  sd[threadIdx.x] = (i < N) ? deg[i] : 0;
  __syncthreads();
  for (int s = 128; s > 0; s >>= 1) {
    if (threadIdx.x < s) sd[threadIdx.x] += sd[threadIdx.x + s];
    __syncthreads();
  }
  if (threadIdx.x == 0) bsum[blockIdx.x] = sd[0];
}

// parallel exclusive scan of bsum[0..nb) with one 256-thread block
__global__ __launch_bounds__(256)
void k_scanb(int* __restrict__ bsum, int nb) {
  __shared__ int part[256];
  int tid = threadIdx.x;
  int per = (nb + 255) / 256;
  int beg = tid * per;
  int end = beg + per; if (end > nb) end = nb;
  int s = 0;
  for (int i = beg; i < end; i++) s += bsum[i];
  part[tid] = s;
  __syncthreads();
  for (int off = 1; off < 256; off <<= 1) {
    int t = (tid >= off) ? part[tid - off] : 0;
    __syncthreads();
    part[tid] += t;
    __syncthreads();
  }
  int run = part[tid] - s;   // exclusive prefix of this chunk
  for (int i = beg; i < end; i++) { int v = bsum[i]; bsum[i] = run; run += v; }
}

// rowptr + dinv fused (deg already loaded here)
__global__ void k_rowptr(const int* __restrict__ deg, const int* __restrict__ bsum,
                         int* __restrict__ rowptr, float* __restrict__ dinvf, int N) {
  __shared__ int sc[256];
  int tid = threadIdx.x;
  int i = blockIdx.x * 256 + tid;
  int v = (i < N) ? deg[i] : 0;
  sc[tid] = v;
  __syncthreads();
  for (int off = 1; off < 256; off <<= 1) {
    int t = (tid >= off) ? sc[tid - off] : 0;
    __syncthreads();
    sc[tid] += t;
    __syncthreads();
  }
  if (i < N) {
    rowptr[i] = bsum[blockIdx.x] + sc[tid] - v;   // exclusive
    dinvf[i] = rsqrtf((float)v + 1.0f);           // +1 self-loop
  }
  if (i == N - 1) rowptr[N] = bsum[blockIdx.x] + sc[tid];  // total = E
}

__global__ void k_fill(const int* __restrict__ src, const int* __restrict__ dst,
                       const int* __restrict__ rowptr, int* __restrict__ cursor,
                       int* __restrict__ adj, int E) {
  int e = blockIdx.x * blockDim.x + threadIdx.x;
  if (e >= E) return;
  int d = dst[e];
  int p = atomicAdd(&cursor[d], 1);
  adj[rowptr[d] + p] = src[e];
}

// ---------------- GCN dense parts ----------------

__global__ void k_xw1(const float* __restrict__ x, const float* __restrict__ W1,
                      const float* __restrict__ dinv, float* __restrict__ A, int N) {
  int i = blockIdx.x * blockDim.x + threadIdx.x;
  if (i >= N) return;
  float4 xi = ((const float4*)x)[i];
  float di = dinv[i];
  #pragma unroll
  for (int c = 0; c < 8; c++) {
    float s = xi.x * W1[c] + xi.y * W1[8 + c] + xi.z * W1[16 + c] + xi.w * W1[24 + c];
    A[(size_t)i * 8 + c] = s * di;
  }
}

__global__ void k_gather_l1(const float* __restrict__ A, const int* __restrict__ rowptr,
                            const int* __restrict__ adj, const float* __restrict__ dinv,
                            const float* __restrict__ b1, const float* __restrict__ W2,
                            float* __restrict__ A2, int N) {
  int i = blockIdx.x * blockDim.x + threadIdx.x;
  if (i >= N) return;
  const float4* Ai = (const float4*)(A + (size_t)i * 8);
  float4 s0 = Ai[0], s1 = Ai[1];
  int beg = rowptr[i], end = rowptr[i + 1];
  for (int j = beg; j < end; j++) {
    const float4* As = (const float4*)(A + (size_t)adj[j] * 8);
    float4 a0 = As[0], a1 = As[1];
    s0.x += a0.x; s0.y += a0.y; s0.z += a0.z; s0.w += a0.w;
    s1.x += a1.x; s1.y += a1.y; s1.z += a1.z; s1.w += a1.w;
  }
  float di = dinv[i];
  float h[8];
  h[0] = fmaxf(s0.x * di + b1[0], 0.f); h[1] = fmaxf(s0.y * di + b1[1], 0.f);
  h[2] = fmaxf(s0.z * di + b1[2], 0.f); h[3] = fmaxf(s0.w * di + b1[3], 0.f);
  h[4] = fmaxf(s1.x * di + b1[4], 0.f); h[5] = fmaxf(s1.y * di + b1[5], 0.f);
  h[6] = fmaxf(s1.z * di + b1[6], 0.f); h[7] = fmaxf(s1.w * di + b1[7], 0.f);
  #pragma unroll
  for (int c = 0; c < 8; c++) {
    float a = 0.f;
    #pragma unroll
    for (int k = 0; k < 8; k++) a += h[k] * W2[k * 8 + c];
    A2[(size_t)i * 8 + c] = a * di;
  }
}

__global__ void k_gather_l2(const float* __restrict__ A2, const int* __restrict__ rowptr,
                            const int* __restrict__ adj, const float* __restrict__ dinv,
                            const float* __restrict__ b2, const int* __restrict__ batch,
                            const int* __restrict__ cum, float* __restrict__ dense, int N) {
  int i = blockIdx.x * blockDim.x + threadIdx.x;
  if (i >= N) return;
  const float4* Ai = (const float4*)(A2 + (size_t)i * 8);
  float4 s0 = Ai[0], s1 = Ai[1];
  int beg = rowptr[i], end = rowptr[i + 1];
  for (int j = beg; j < end; j++) {
    const float4* As = (const float4*)(A2 + (size_t)adj[j] * 8);
    float4 a0 = As[0], a1 = As[1];
    s0.x += a0.x; s0.y += a0.y; s0.z += a0.z; s0.w += a0.w;
    s1.x += a1.x; s1.y += a1.y; s1.z += a1.z; s1.w += a1.w;
  }
  float di = dinv[i];
  float h[8];
  h[0] = fmaxf(s0.x * di + b2[0], 0.f); h[1] = fmaxf(s0.y * di + b2[1], 0.f);
  h[2] = fmaxf(s0.z * di + b2[2], 0.f); h[3] = fmaxf(s0.w * di + b2[3], 0.f);
  h[4] = fmaxf(s1.x * di + b2[4], 0.f); h[5] = fmaxf(s1.y * di + b2[5], 0.f);
  h[6] = fmaxf(s1.z * di + b2[6], 0.f); h[7] = fmaxf(s1.w * di + b2[7], 0.f);
  int b = batch[i];
  int pos = i - cum[b];
  #pragma unroll
  for (int c = 0; c < 8; c++)
    dense[((size_t)(b * 8 + c)) * MAXN + pos] = h[c];
}

// ---------------- conv1d(k=5,'same') + relu + mean-pool2 — scalar weights, no LDS ----------------
// grid (BG, COG, LT) = 1024 blocks (4/CU). Weights read via wave-uniform (readfirstlane'd)
// addresses -> s_load into SGPRs, broadcast into FMAs: no LDS, no barriers.
// ci loop unrolled by 2 with A/B register ping-pong so next-ci loads issue before this-ci FMAs.
template<int CIN, int COUT, int L, int COG>
__global__ __launch_bounds__(256, 4)
void k_conv(const float* __restrict__ in, const float* __restrict__ w,
            const float* __restrict__ bias, float* __restrict__ out) {
  constexpr int LOUT = L / 2;
  constexpr int COPB = COUT / COG;      // 16 out-channels per block
  constexpr int NCO = COPB / 4;         // 4 per wave
  constexpr int TP = 256;               // pooled positions per tile

  const int lane = threadIdx.x & 63;
  const int wv = threadIdx.x >> 6;
  const int co0 = __builtin_amdgcn_readfirstlane(blockIdx.y * COPB + wv * NCO);
  const int p0 = blockIdx.z * TP + lane * 4;   // first pooled pos (mult of 4)
  const int a0 = 2 * p0 - 4;                   // aligned load base
  const bool lz = (p0 == 0);
  const float* __restrict__ inb = in + (size_t)blockIdx.x * CIN * L;

  int bas[4];
  #pragma unroll
  for (int m = 0; m < 4; m++) {
    int rb = a0 + 4 * m;
    rb = rb < 0 ? 0 : rb;
    bas[m] = rb > (L - 4) ? (L - 4) : rb;
  }

  float acc[NCO][8];
  #pragma unroll
  for (int g = 0; g < NCO; g++)
    #pragma unroll
    for (int p = 0; p < 8; p++) acc[g][p] = 0.f;

  // FMA block for one ci, inputs in 4 float4 regs, weights via scalar loads
  auto fmab = [&](float4 q0, float4 q1, float4 q2, float4 q3, int ci) {
    float r[16];
    r[0] = q0.x; r[1] = q0.y; r[2] = q0.z; r[3] = q0.w;
    r[4] = q1.x; r[5] = q1.y; r[6] = q1.z; r[7] = q1.w;
    r[8] = q2.x; r[9] = q2.y; r[10] = q2.z; r[11] = q2.w;
    r[12] = q3.x; r[13] = q3.y; r[14] = q3.z; r[15] = q3.w;
    if (lz) { r[2] = 0.f; r[3] = 0.f; }   // cols -2,-1 (left pad)
    #pragma unroll
    for (int g = 0; g < NCO; g++) {
      const float* wg = w + ((size_t)(co0 + g) * CIN + ci) * 5;  // wave-uniform -> s_load
      float v0 = wg[0], v1 = wg[1], v2 = wg[2], v3 = wg[3], v4 = wg[4];
      #pragma unroll
      for (int p = 0; p < 8; p++)
        acc[g][p] += v0 * r[p + 2] + v1 * r[p + 3] + v2 * r[p + 4]
                   + v3 * r[p + 5] + v4 * r[p + 6];
    }
  };

  // ci unroll-2 ping-pong: loads for the next ci issue before current FMAs retire
  float4 A0, A1, A2, A3, B0, B1, B2, B3;
  {
    const float* s = inb;
    A0 = *(const float4*)(s + bas[0]); A1 = *(const float4*)(s + bas[1]);
    A2 = *(const float4*)(s + bas[2]); A3 = *(const float4*)(s + bas[3]);
  }
  for (int ci = 0; ci < CIN; ci += 2) {
    {
      const float* s = inb + (size_t)(ci + 1) * L;
      B0 = *(const float4*)(s + bas[0]); B1 = *(const float4*)(s + bas[1]);
      B2 = *(const float4*)(s + bas[2]); B3 = *(const float4*)(s + bas[3]);
    }
    fmab(A0, A1, A2, A3, ci);
    if (ci + 2 < CIN) {
      const float* s = inb + (size_t)(ci + 2) * L;
      A0 = *(const float4*)(s + bas[0]); A1 = *(const float4*)(s + bas[1]);
      A2 = *(const float4*)(s + bas[2]); A3 = *(const float4*)(s + bas[3]);
    }
    fmab(B0, B1, B2, B3, ci + 1);
  }

  #pragma unroll
  for (int g = 0; g < NCO; g++) {
    int co = co0 + g;
    float bv = bias[co];
    float tmp[4];
    #pragma unroll
    for (int m = 0; m < 4; m++) {
      float y0 = fmaxf(acc[g][2 * m] + bv, 0.f);
      float y1 = fmaxf(acc[g][2 * m + 1] + bv, 0.f);
      tmp[m] = 0.5f * (y0 + y1);
    }
    float* op = out + (size_t)(blockIdx.x * COUT + co) * LOUT + p0;
    if constexpr (LOUT % 4 == 0) {
      if (p0 + 4 <= LOUT) {
        *(float4*)op = make_float4(tmp[0], tmp[1], tmp[2], tmp[3]);
      } else {
        #pragma unroll
        for (int m = 0; m < 4; m++) if (p0 + m < LOUT) op[m] = tmp[m];
      }
    } else {  // LOUT % 2 == 0 (conv3: 250)
      #pragma unroll
      for (int m2 = 0; m2 < 2; m2++) {
        int p = p0 + 2 * m2;
        if (p + 1 < LOUT) {
          *(float2*)(op + 2 * m2) = make_float2(tmp[2 * m2], tmp[2 * m2 + 1]);
        } else if (p < LOUT) {
          op[2 * m2] = tmp[2 * m2];
        }
      }
    }
  }
}

// ---------------- fused head: segment means + MLP (one block per graph) ----------------
__global__ __launch_bounds__(256)
void k_head(const float* __restrict__ xp, const int* __restrict__ cum,
            const float* __restrict__ fw1, const float* __restrict__ fb1,
            const float* __restrict__ fw2, const float* __restrict__ fb2,
            float* __restrict__ out) {
  constexpr int LC = MAXN / 8;   // 250
  __shared__ float seg[640];
  __shared__ float hid[100];
  int b = blockIdx.x;
  int valid = (cum[b + 1] - cum[b]) >> 3;
  int base = valid / NPARTS, rem = valid % NPARTS;
  for (int idx = threadIdx.x; idx < 64 * NPARTS; idx += 256) {
    int c = idx / NPARTS, j = idx % NPARTS;
    int size = base + (j < rem ? 1 : 0);
    int start = j * base + (j < rem ? j : rem);
    const float* p = xp + ((size_t)b * 64 + c) * LC + start;
    float s = 0.f;
    for (int t = 0; t < size; t++) s += p[t];
    seg[idx] = s / (float)size;   // seg[c*10+j]
  }
  __syncthreads();
  int t = threadIdx.x;
  if (t < 100) {
    float acc = fb1[t];
    for (int k = 0; k < 640; k++) acc += seg[k] * fw1[(size_t)k * 100 + t];
    hid[t] = fmaxf(acc, 0.f);
  }
  __syncthreads();
  if (t < 2) {
    float acc = fb2[t];
    for (int k = 0; k < 100; k++) acc += hid[k] * fw2[k * 2 + t];
    out[b * 2 + t] = acc;
  }
}

extern "C" void kernel_launch(void* const* d_in, const int* in_sizes, int n_in,
                              void* d_out, int out_size, void* d_ws, size_t ws_size,
                              hipStream_t stream) {
  const float* x   = (const float*)d_in[0];
  const int*   ei  = (const int*)d_in[1];
  const int* batch = (const int*)d_in[2];
  const float* W1  = (const float*)d_in[3];
  const float* b1  = (const float*)d_in[4];
  const float* W2  = (const float*)d_in[5];
  const float* b2  = (const float*)d_in[6];
  const float* cw1 = (const float*)d_in[7];
  const float* cb1 = (const float*)d_in[8];
  const float* cw2 = (const float*)d_in[9];
  const float* cb2 = (const float*)d_in[10];
  const float* cw3 = (const float*)d_in[11];
  const float* cb3 = (const float*)d_in[12];
  const float* fw1 = (const float*)d_in[13];
  const float* fb1 = (const float*)d_in[14];
  const float* fw2 = (const float*)d_in[15];
  const float* fb2 = (const float*)d_in[16];
  float* outp = (float*)d_out;

  int N = in_sizes[0] / 4;
  int E = in_sizes[1] / 2;
  size_t N8 = (size_t)N * 8;
  int nbN = (N + 255) / 256, nbE = (E + 255) / 256;

  float* wsf  = (float*)d_ws;
  float* A    = wsf;
  float* Bb   = A + N8;              // A2 for layer 2
  int* degI   = (int*)(Bb + N8);     // N ints
  int* cursor = degI + N;            // N ints (adjacent -> one memset)
  float* dinv = (float*)(cursor + N);// N floats
  int* cum    = (int*)(dinv + N);    // BG+1 ints
  float* D0   = (float*)(((uintptr_t)(cum + BG + 1) + 255) & ~(uintptr_t)255);
  float* D1   = D0 + (size_t)BG * 8 * MAXN;

  // CSR temporaries aliased into D1 (D1 first written by conv1, after fill/gathers)
  int* rowptr = (int*)D1;            // N+1
  int* adj    = rowptr + (N + 1);    // E
  int* bsum   = adj + E;             // nbN

  // --- boundaries (no atomics) ---
  k_bounds<<<nbN, 256, 0, stream>>>(batch, cum, N);

  // --- CSR build ---
  hipMemsetAsync(degI, 0, 2 * (size_t)N * sizeof(int), stream);   // degI + cursor
  k_deg_int<<<nbE, 256, 0, stream>>>(ei + E, degI, E);
  k_blocksum<<<nbN, 256, 0, stream>>>(degI, bsum, N);
  k_scanb<<<1, 256, 0, stream>>>(bsum, nbN);
  k_rowptr<<<nbN, 256, 0, stream>>>(degI, bsum, rowptr, dinv, N);
  k_fill<<<nbE, 256, 0, stream>>>(ei, ei + E, rowptr, cursor, adj, E);

  // --- GCN (gather, no atomics) ---
  k_xw1<<<nbN, 256, 0, stream>>>(x, W1, dinv, A, N);
  k_gather_l1<<<nbN, 256, 0, stream>>>(A, rowptr, adj, dinv, b1, W2, Bb, N);
  hipMemsetAsync(D0, 0, (size_t)BG * 8 * MAXN * sizeof(float), stream);
  k_gather_l2<<<nbN, 256, 0, stream>>>(Bb, rowptr, adj, dinv, b2, batch, cum, D0, N);

  // --- convs: scalar weights, no LDS, 1024 blocks (4/CU), ci unroll-2 ping-pong ---
  k_conv<8, 16, 2000, 1><<<dim3(BG, 1, 4), 256, 0, stream>>>(D0, cw1, cb1, D1);
  k_conv<16, 32, 1000, 2><<<dim3(BG, 2, 2), 256, 0, stream>>>(D1, cw2, cb2, D0);
  k_conv<32, 64, 500, 4><<<dim3(BG, 4, 1), 256, 0, stream>>>(D0, cw3, cb3, D1);

  // --- fused segment means + MLP ---
  k_head<<<BG, 256, 0, stream>>>(D1, cum, fw1, fb1, fw2, fb2, outp);
}

// Round 14
// 160.613 us; speedup vs baseline: 2.8259x; 1.0113x over previous
//
#include <hip/hip_runtime.h>
#include <cstdint>

constexpr int BG = 256;        // graphs
constexpr int MAXN = 2000;
constexpr int NPARTS = 10;

// ---------------- utility: fast zero (grid-stride int4) ----------------

__global__ void k_zeroi(int4* __restrict__ p, size_t n4) {
  size_t i = (size_t)blockIdx.x * blockDim.x + threadIdx.x;
  size_t stride = (size_t)gridDim.x * blockDim.x;
  for (; i < n4; i += stride) p[i] = make_int4(0, 0, 0, 0);
}

// zero only padding positions of dense: pos in [cnt, MAXN) per graph/channel
__global__ void k_zero_pad(float* __restrict__ dense, const int* __restrict__ cum) {
  int b = blockIdx.x;
  int cnt = cum[b + 1] - cum[b];
  for (int pos = cnt + threadIdx.x; pos < MAXN; pos += blockDim.x) {
    #pragma unroll
    for (int c = 0; c < 8; c++)
      dense[((size_t)(b * 8 + c)) * MAXN + pos] = 0.f;
  }
}

// ---------------- batch boundaries (no atomics; batch is sorted) ----------------

__global__ void k_bounds(const int* __restrict__ batch, int* __restrict__ cum, int N) {
  int i = blockIdx.x * blockDim.x + threadIdx.x;
  if (i >= N) return;
  int b = batch[i];
  if (i == 0) cum[b] = 0;
  else if (batch[i - 1] != b) cum[b] = i;
  if (i == N - 1) cum[BG] = N;
}

// ---------------- CSR build ----------------

__global__ void k_deg_int(const int* __restrict__ dst, int* __restrict__ deg, int E) {
  int e = blockIdx.x * blockDim.x + threadIdx.x;
  if (e < E) atomicAdd(&deg[dst[e]], 1);
}

__global__ void k_blocksum(const int* __restrict__ deg, int* __restrict__ bsum, int N) {
  __shared__ int sd[256];
  int i = blockIdx.x * 256 + threadIdx.x;
  sd[threadIdx.x] = (i < N) ? deg[i] : 0;
  __syncthreads();
  for (int s = 128; s > 0; s >>= 1) {
    if (threadIdx.x < s) sd[threadIdx.x] += sd[threadIdx.x + s];
    __syncthreads();
  }
  if (threadIdx.x == 0) bsum[blockIdx.x] = sd[0];
}

// parallel exclusive scan of bsum[0..nb) with one 256-thread block
__global__ __launch_bounds__(256)
void k_scanb(int* __restrict__ bsum, int nb) {
  __shared__ int part[256];
  int tid = threadIdx.x;
  int per = (nb + 255) / 256;
  int beg = tid * per;
  int end = beg + per; if (end > nb) end = nb;
  int s = 0;
  for (int i = beg; i < end; i++) s += bsum[i];
  part[tid] = s;
  __syncthreads();
  for (int off = 1; off < 256; off <<= 1) {
    int t = (tid >= off) ? part[tid - off] : 0;
    __syncthreads();
    part[tid] += t;
    __syncthreads();
  }
  int run = part[tid] - s;   // exclusive prefix of this chunk
  for (int i = beg; i < end; i++) { int v = bsum[i]; bsum[i] = run; run += v; }
}

// rowptr + dinv fused (deg already loaded here)
__global__ void k_rowptr(const int* __restrict__ deg, const int* __restrict__ bsum,
                         int* __restrict__ rowptr, float* __restrict__ dinvf, int N) {
  __shared__ int sc[256];
  int tid = threadIdx.x;
  int i = blockIdx.x * 256 + tid;
  int v = (i < N) ? deg[i] : 0;
  sc[tid] = v;
  __syncthreads();
  for (int off = 1; off < 256; off <<= 1) {
    int t = (tid >= off) ? sc[tid - off] : 0;
    __syncthreads();
    sc[tid] += t;
    __syncthreads();
  }
  if (i < N) {
    rowptr[i] = bsum[blockIdx.x] + sc[tid] - v;   // exclusive
    dinvf[i] = rsqrtf((float)v + 1.0f);           // +1 self-loop
  }
  if (i == N - 1) rowptr[N] = bsum[blockIdx.x] + sc[tid];  // total = E
}

__global__ void k_fill(const int* __restrict__ src, const int* __restrict__ dst,
                       const int* __restrict__ rowptr, int* __restrict__ cursor,
                       int* __restrict__ adj, int E) {
  int e = blockIdx.x * blockDim.x + threadIdx.x;
  if (e >= E) return;
  int d = dst[e];
  int p = atomicAdd(&cursor[d], 1);
  adj[rowptr[d] + p] = src[e];
}

// ---------------- GCN dense parts ----------------

__global__ void k_xw1(const float* __restrict__ x, const float* __restrict__ W1,
                      const float* __restrict__ dinv, float* __restrict__ A, int N) {
  int i = blockIdx.x * blockDim.x + threadIdx.x;
  if (i >= N) return;
  float4 xi = ((const float4*)x)[i];
  float di = dinv[i];
  #pragma unroll
  for (int c = 0; c < 8; c++) {
    float s = xi.x * W1[c] + xi.y * W1[8 + c] + xi.z * W1[16 + c] + xi.w * W1[24 + c];
    A[(size_t)i * 8 + c] = s * di;
  }
}

__global__ void k_gather_l1(const float* __restrict__ A, const int* __restrict__ rowptr,
                            const int* __restrict__ adj, const float* __restrict__ dinv,
                            const float* __restrict__ b1, const float* __restrict__ W2,
                            float* __restrict__ A2, int N) {
  int i = blockIdx.x * blockDim.x + threadIdx.x;
  if (i >= N) return;
  const float4* Ai = (const float4*)(A + (size_t)i * 8);
  float4 s0 = Ai[0], s1 = Ai[1];
  int beg = rowptr[i], end = rowptr[i + 1];
  for (int j = beg; j < end; j++) {
    const float4* As = (const float4*)(A + (size_t)adj[j] * 8);
    float4 a0 = As[0], a1 = As[1];
    s0.x += a0.x; s0.y += a0.y; s0.z += a0.z; s0.w += a0.w;
    s1.x += a1.x; s1.y += a1.y; s1.z += a1.z; s1.w += a1.w;
  }
  float di = dinv[i];
  float h[8];
  h[0] = fmaxf(s0.x * di + b1[0], 0.f); h[1] = fmaxf(s0.y * di + b1[1], 0.f);
  h[2] = fmaxf(s0.z * di + b1[2], 0.f); h[3] = fmaxf(s0.w * di + b1[3], 0.f);
  h[4] = fmaxf(s1.x * di + b1[4], 0.f); h[5] = fmaxf(s1.y * di + b1[5], 0.f);
  h[6] = fmaxf(s1.z * di + b1[6], 0.f); h[7] = fmaxf(s1.w * di + b1[7], 0.f);
  #pragma unroll
  for (int c = 0; c < 8; c++) {
    float a = 0.f;
    #pragma unroll
    for (int k = 0; k < 8; k++) a += h[k] * W2[k * 8 + c];
    A2[(size_t)i * 8 + c] = a * di;
  }
}

__global__ void k_gather_l2(const float* __restrict__ A2, const int* __restrict__ rowptr,
                            const int* __restrict__ adj, const float* __restrict__ dinv,
                            const float* __restrict__ b2, const int* __restrict__ batch,
                            const int* __restrict__ cum, float* __restrict__ dense, int N) {
  int i = blockIdx.x * blockDim.x + threadIdx.x;
  if (i >= N) return;
  const float4* Ai = (const float4*)(A2 + (size_t)i * 8);
  float4 s0 = Ai[0], s1 = Ai[1];
  int beg = rowptr[i], end = rowptr[i + 1];
  for (int j = beg; j < end; j++) {
    const float4* As = (const float4*)(A2 + (size_t)adj[j] * 8);
    float4 a0 = As[0], a1 = As[1];
    s0.x += a0.x; s0.y += a0.y; s0.z += a0.z; s0.w += a0.w;
    s1.x += a1.x; s1.y += a1.y; s1.z += a1.z; s1.w += a1.w;
  }
  float di = dinv[i];
  float h[8];
  h[0] = fmaxf(s0.x * di + b2[0], 0.f); h[1] = fmaxf(s0.y * di + b2[1], 0.f);
  h[2] = fmaxf(s0.z * di + b2[2], 0.f); h[3] = fmaxf(s0.w * di + b2[3], 0.f);
  h[4] = fmaxf(s1.x * di + b2[4], 0.f); h[5] = fmaxf(s1.y * di + b2[5], 0.f);
  h[6] = fmaxf(s1.z * di + b2[6], 0.f); h[7] = fmaxf(s1.w * di + b2[7], 0.f);
  int b = batch[i];
  int pos = i - cum[b];
  #pragma unroll
  for (int c = 0; c < 8; c++)
    dense[((size_t)(b * 8 + c)) * MAXN + pos] = h[c];
}

// ---------------- conv1d(k=5,'same') + relu + mean-pool2 — scalar weights, no LDS ----------------
template<int CIN, int COUT, int L, int COG>
__global__ __launch_bounds__(256, 4)
void k_conv(const float* __restrict__ in, const float* __restrict__ w,
            const float* __restrict__ bias, float* __restrict__ out) {
  constexpr int LOUT = L / 2;
  constexpr int COPB = COUT / COG;      // 16 out-channels per block
  constexpr int NCO = COPB / 4;         // 4 per wave
  constexpr int TP = 256;               // pooled positions per tile

  const int lane = threadIdx.x & 63;
  const int wv = threadIdx.x >> 6;
  const int co0 = __builtin_amdgcn_readfirstlane(blockIdx.y * COPB + wv * NCO);
  const int p0 = blockIdx.z * TP + lane * 4;   // first pooled pos (mult of 4)
  const int a0 = 2 * p0 - 4;                   // aligned load base
  const bool lz = (p0 == 0);
  const float* __restrict__ inb = in + (size_t)blockIdx.x * CIN * L;

  int bas[4];
  #pragma unroll
  for (int m = 0; m < 4; m++) {
    int rb = a0 + 4 * m;
    rb = rb < 0 ? 0 : rb;
    bas[m] = rb > (L - 4) ? (L - 4) : rb;
  }

  float acc[NCO][8];
  #pragma unroll
  for (int g = 0; g < NCO; g++)
    #pragma unroll
    for (int p = 0; p < 8; p++) acc[g][p] = 0.f;

  auto fmab = [&](float4 q0, float4 q1, float4 q2, float4 q3, int ci) {
    float r[16];
    r[0] = q0.x; r[1] = q0.y; r[2] = q0.z; r[3] = q0.w;
    r[4] = q1.x; r[5] = q1.y; r[6] = q1.z; r[7] = q1.w;
    r[8] = q2.x; r[9] = q2.y; r[10] = q2.z; r[11] = q2.w;
    r[12] = q3.x; r[13] = q3.y; r[14] = q3.z; r[15] = q3.w;
    if (lz) { r[2] = 0.f; r[3] = 0.f; }   // cols -2,-1 (left pad)
    #pragma unroll
    for (int g = 0; g < NCO; g++) {
      const float* wg = w + ((size_t)(co0 + g) * CIN + ci) * 5;  // wave-uniform -> s_load
      float v0 = wg[0], v1 = wg[1], v2 = wg[2], v3 = wg[3], v4 = wg[4];
      #pragma unroll
      for (int p = 0; p < 8; p++)
        acc[g][p] += v0 * r[p + 2] + v1 * r[p + 3] + v2 * r[p + 4]
                   + v3 * r[p + 5] + v4 * r[p + 6];
    }
  };

  float4 A0, A1, A2, A3, B0, B1, B2, B3;
  {
    const float* s = inb;
    A0 = *(const float4*)(s + bas[0]); A1 = *(const float4*)(s + bas[1]);
    A2 = *(const float4*)(s + bas[2]); A3 = *(const float4*)(s + bas[3]);
  }
  for (int ci = 0; ci < CIN; ci += 2) {
    {
      const float* s = inb + (size_t)(ci + 1) * L;
      B0 = *(const float4*)(s + bas[0]); B1 = *(const float4*)(s + bas[1]);
      B2 = *(const float4*)(s + bas[2]); B3 = *(const float4*)(s + bas[3]);
    }
    fmab(A0, A1, A2, A3, ci);
    if (ci + 2 < CIN) {
      const float* s = inb + (size_t)(ci + 2) * L;
      A0 = *(const float4*)(s + bas[0]); A1 = *(const float4*)(s + bas[1]);
      A2 = *(const float4*)(s + bas[2]); A3 = *(const float4*)(s + bas[3]);
    }
    fmab(B0, B1, B2, B3, ci + 1);
  }

  #pragma unroll
  for (int g = 0; g < NCO; g++) {
    int co = co0 + g;
    float bv = bias[co];
    float tmp[4];
    #pragma unroll
    for (int m = 0; m < 4; m++) {
      float y0 = fmaxf(acc[g][2 * m] + bv, 0.f);
      float y1 = fmaxf(acc[g][2 * m + 1] + bv, 0.f);
      tmp[m] = 0.5f * (y0 + y1);
    }
    float* op = out + (size_t)(blockIdx.x * COUT + co) * LOUT + p0;
    if constexpr (LOUT % 4 == 0) {
      if (p0 + 4 <= LOUT) {
        *(float4*)op = make_float4(tmp[0], tmp[1], tmp[2], tmp[3]);
      } else {
        #pragma unroll
        for (int m = 0; m < 4; m++) if (p0 + m < LOUT) op[m] = tmp[m];
      }
    } else {  // LOUT % 2 == 0 (conv3: 250)
      #pragma unroll
      for (int m2 = 0; m2 < 2; m2++) {
        int p = p0 + 2 * m2;
        if (p + 1 < LOUT) {
          *(float2*)(op + 2 * m2) = make_float2(tmp[2 * m2], tmp[2 * m2 + 1]);
        } else if (p < LOUT) {
          op[2 * m2] = tmp[2 * m2];
        }
      }
    }
  }
}

// ---------------- fused head: segment means + MLP (one block per graph) ----------------
__global__ __launch_bounds__(256)
void k_head(const float* __restrict__ xp, const int* __restrict__ cum,
            const float* __restrict__ fw1, const float* __restrict__ fb1,
            const float* __restrict__ fw2, const float* __restrict__ fb2,
            float* __restrict__ out) {
  constexpr int LC = MAXN / 8;   // 250
  __shared__ float seg[640];
  __shared__ float hid[100];
  int b = blockIdx.x;
  int valid = (cum[b + 1] - cum[b]) >> 3;
  int base = valid / NPARTS, rem = valid % NPARTS;
  for (int idx = threadIdx.x; idx < 64 * NPARTS; idx += 256) {
    int c = idx / NPARTS, j = idx % NPARTS;
    int size = base + (j < rem ? 1 : 0);
    int start = j * base + (j < rem ? j : rem);
    const float* p = xp + ((size_t)b * 64 + c) * LC + start;
    float s = 0.f;
    for (int t = 0; t < size; t++) s += p[t];
    seg[idx] = s / (float)size;   // seg[c*10+j]
  }
  __syncthreads();
  int t = threadIdx.x;
  if (t < 100) {
    float acc = fb1[t];
    for (int k = 0; k < 640; k++) acc += seg[k] * fw1[(size_t)k * 100 + t];
    hid[t] = fmaxf(acc, 0.f);
  }
  __syncthreads();
  if (t < 2) {
    float acc = fb2[t];
    for (int k = 0; k < 100; k++) acc += hid[k] * fw2[k * 2 + t];
    out[b * 2 + t] = acc;
  }
}

extern "C" void kernel_launch(void* const* d_in, const int* in_sizes, int n_in,
                              void* d_out, int out_size, void* d_ws, size_t ws_size,
                              hipStream_t stream) {
  const float* x   = (const float*)d_in[0];
  const int*   ei  = (const int*)d_in[1];
  const int* batch = (const int*)d_in[2];
  const float* W1  = (const float*)d_in[3];
  const float* b1  = (const float*)d_in[4];
  const float* W2  = (const float*)d_in[5];
  const float* b2  = (const float*)d_in[6];
  const float* cw1 = (const float*)d_in[7];
  const float* cb1 = (const float*)d_in[8];
  const float* cw2 = (const float*)d_in[9];
  const float* cb2 = (const float*)d_in[10];
  const float* cw3 = (const float*)d_in[11];
  const float* cb3 = (const float*)d_in[12];
  const float* fw1 = (const float*)d_in[13];
  const float* fb1 = (const float*)d_in[14];
  const float* fw2 = (const float*)d_in[15];
  const float* fb2 = (const float*)d_in[16];
  float* outp = (float*)d_out;

  int N = in_sizes[0] / 4;
  int E = in_sizes[1] / 2;
  size_t N8 = (size_t)N * 8;
  int nbN = (N + 255) / 256, nbE = (E + 255) / 256;

  float* wsf  = (float*)d_ws;
  float* A    = wsf;
  float* Bb   = A + N8;              // A2 for layer 2
  int* degI   = (int*)(Bb + N8);     // N ints
  int* cursor = degI + N;            // N ints (adjacent -> one zero pass)
  float* dinv = (float*)(cursor + N);// N floats
  int* cum    = (int*)(dinv + N);    // BG+1 ints
  float* D0   = (float*)(((uintptr_t)(cum + BG + 1) + 255) & ~(uintptr_t)255);
  float* D1   = D0 + (size_t)BG * 8 * MAXN;

  // CSR temporaries aliased into D1 (D1 first written by conv1, after fill/gathers)
  int* rowptr = (int*)D1;            // N+1
  int* adj    = rowptr + (N + 1);    // E
  int* bsum   = adj + E;             // nbN

  // --- boundaries (no atomics) ---
  k_bounds<<<nbN, 256, 0, stream>>>(batch, cum, N);

  // --- CSR build ---
  k_zeroi<<<1024, 256, 0, stream>>>((int4*)degI, (size_t)(2 * N) / 4);  // degI + cursor
  k_deg_int<<<nbE, 256, 0, stream>>>(ei + E, degI, E);
  k_blocksum<<<nbN, 256, 0, stream>>>(degI, bsum, N);
  k_scanb<<<1, 256, 0, stream>>>(bsum, nbN);
  k_rowptr<<<nbN, 256, 0, stream>>>(degI, bsum, rowptr, dinv, N);
  k_fill<<<nbE, 256, 0, stream>>>(ei, ei + E, rowptr, cursor, adj, E);

  // --- GCN (gather, no atomics) ---
  k_xw1<<<nbN, 256, 0, stream>>>(x, W1, dinv, A, N);
  k_gather_l1<<<nbN, 256, 0, stream>>>(A, rowptr, adj, dinv, b1, W2, Bb, N);
  k_zero_pad<<<BG, 256, 0, stream>>>(D0, cum);   // zero only pos >= cnt
  k_gather_l2<<<nbN, 256, 0, stream>>>(Bb, rowptr, adj, dinv, b2, batch, cum, D0, N);

  // --- convs: scalar weights, no LDS, 1024 blocks (4/CU), ci unroll-2 ping-pong ---
  k_conv<8, 16, 2000, 1><<<dim3(BG, 1, 4), 256, 0, stream>>>(D0, cw1, cb1, D1);
  k_conv<16, 32, 1000, 2><<<dim3(BG, 2, 2), 256, 0, stream>>>(D1, cw2, cb2, D0);
  k_conv<32, 64, 500, 4><<<dim3(BG, 4, 1), 256, 0, stream>>>(D0, cw3, cb3, D1);

  // --- fused segment means + MLP ---
  k_head<<<BG, 256, 0, stream>>>(D1, cum, fw1, fb1, fw2, fb2, outp);
}